// Round 5
// baseline (166.945 us; speedup 1.0000x reference)
//
#include <hip/hip_runtime.h>
#include <hip/hip_fp16.h>

#define BB 8
#define CC 7
#define HH 512
#define WW 512
#define HW (HH*WW)

// ws layout: [0,224) 28 doubles:
//   [0]=focal [1]=bce [2..8]=sumP [9..15]=inter [16..22]=cnt [23..27]=topo_num

// One block = 32x32 output pixels of one image. LDS plan (19.25 KB total ->
// 8 blocks/CU, 100% occupancy):
//   sp  : f16 probs, PLANAR (7 planes x 1164), stride-2 reads = conflict-free.
//         Region [0,16296). Aliases bm/hm scratch (dead before phase A).
//   st  : targets +-3 halo, u8[38*38]           @ 16296
//   rm  : per-interior-pixel region byte u8[1024]@ 17744
//   sw  : class weights f32[8]                  @ 18768
//   sred: cross-wave reduce f32[112]            @ 18800
//   bm  : boundary bits u8[36*36]  @ 0    (scratch, dead after h-OR)
//   hm  : horizontal 5-OR u8[36*32]@ 1296 (scratch, dead after v-OR)
// NO per-block __threadfence / ticket (R2/R3: device fence per block ~2x time).
__global__ __launch_bounds__(256) void main_kernel(const float* __restrict__ logits,
                                                   const int* __restrict__ tgt,
                                                   const float* __restrict__ cw,
                                                   double* __restrict__ acc) {
    __shared__ __align__(16) char smem[19248];
    unsigned short* sp = (unsigned short*)smem;
    unsigned char* st = (unsigned char*)(smem + 16296);
    unsigned char* rm = (unsigned char*)(smem + 17744);
    float* sw = (float*)(smem + 18768);
    float* sred = (float*)(smem + 18800);
    unsigned char* bm = (unsigned char*)smem;
    unsigned char* hm = (unsigned char*)(smem + 1296);

    const int tid = threadIdx.x;
    const int b = blockIdx.z;
    const int gx0 = blockIdx.x * 32;
    const int gy0 = blockIdx.y * 32;
    if (tid < 7) sw[tid] = cw[tid];

    const float* lg = logits + (size_t)b * CC * HW;
    const int* tg = tgt + (size_t)b * HW;

    // ---- step 1: targets +-3 ----
    for (int p = tid; p < 1444; p += 256) {
        int iy = p / 38, ix = p - iy * 38;
        int y = gy0 - 3 + iy, x = gx0 - 3 + ix;
        int tv = 255;
        if ((unsigned)y < HH && (unsigned)x < WW) tv = tg[y * WW + x];
        st[p] = (unsigned char)tv;
    }
    __syncthreads();

    // ---- step 2: boundary bits (+-2), zero-padded laplacian semantics ----
    for (int p = tid; p < 1296; p += 256) {
        int by = p / 36, bx = p - by * 36;
        int y = gy0 - 2 + by, x = gx0 - 2 + bx;
        unsigned bits = 0;
        if ((unsigned)y < HH && (unsigned)x < WW) {
            int si = (by + 1) * 38 + (bx + 1);
            int t = st[si];
            unsigned orm = 0; int nfirst = -1, same = 1, ninb = 0;
            int n;
            n = st[si - 38]; if (n != 255) { orm |= 1u << n; if (nfirst < 0) nfirst = n; else same &= (n == nfirst); ninb++; }
            n = st[si + 38]; if (n != 255) { orm |= 1u << n; if (nfirst < 0) nfirst = n; else same &= (n == nfirst); ninb++; }
            n = st[si - 1];  if (n != 255) { orm |= 1u << n; if (nfirst < 0) nfirst = n; else same &= (n == nfirst); ninb++; }
            n = st[si + 1];  if (n != 255) { orm |= 1u << n; if (nfirst < 0) nfirst = n; else same &= (n == nfirst); ninb++; }
            unsigned andm = (ninb == 4 && same) ? (1u << nfirst) : 0u;
            unsigned cbit = 1u << t;
            bits = (orm & ~cbit) | (cbit & ~andm);
        }
        bm[p] = (unsigned char)bits;
    }
    __syncthreads();

    // ---- step 3: horizontal 5-OR ----
    for (int p = tid; p < 1152; p += 256) {
        int hy = p >> 5, hx = p & 31;
        const unsigned char* r = &bm[hy * 36 + hx];
        hm[p] = (unsigned char)(r[0] | r[1] | r[2] | r[3] | r[4]);
    }
    __syncthreads();

    // ---- step 4: vertical 5-OR -> per-pixel region byte ----
#pragma unroll
    for (int k = 0; k < 4; k++) {
        int p = tid + k * 256;
        int cy = p >> 5, cx = p & 31;
        const unsigned char* hc = &hm[cy * 32 + cx];
        rm[p] = (unsigned char)(hc[0] | hc[32] | hc[64] | hc[96] | hc[128]);
    }
    __syncthreads();   // bm/hm dead; sp may now overwrite them

    // ---- phase A: softmax for 34x34 halo -> planar f16 LDS ----
    for (int p = tid; p < 1156; p += 256) {
        int iy = p / 34, ix = p - iy * 34;
        int y = gy0 - 1 + iy, x = gx0 - 1 + ix;
        float pr[7] = {0,0,0,0,0,0,0};
        if ((unsigned)y < HH && (unsigned)x < WW) {
            const float* lp = lg + y * WW + x;
            float e[7]; float se = 0.f;
#pragma unroll
            for (int c = 0; c < 7; c++) { e[c] = __expf(lp[c * HW]); se += e[c]; }
            float inv = 1.0f / se;
#pragma unroll
            for (int c = 0; c < 7; c++) pr[c] = e[c] * inv;
        }
#pragma unroll
        for (int c = 0; c < 7; c++)
            sp[c * 1164 + p] = __half_as_ushort(__float2half_rn(pr[c]));
    }
    __syncthreads();

    // ---- phase B: uniform interior sweep ----
    float accF = 0.f, accB = 0.f;
    float sumP[7] = {0,0,0,0,0,0,0};
    float inter[7] = {0,0,0,0,0,0,0};
    float cnt[7] = {0,0,0,0,0,0,0};
    float num[5] = {0,0,0,0,0};

#pragma unroll
    for (int k = 0; k < 4; k++) {
        int p = tid + k * 256;
        int cy = p >> 5, cx = p & 31;
        int hp = (cy + 1) * 34 + (cx + 1);
        int t = st[(cy + 3) * 38 + (cx + 3)];
        float pr[7];
#pragma unroll
        for (int c = 0; c < 7; c++)
            pr[c] = __half2float(__ushort_as_half(sp[c * 1164 + hp]));

        // focal (register select, no dynamic LDS)
        float p_t = pr[0];
#pragma unroll
        for (int c = 1; c < 7; c++) p_t = (t == c) ? pr[c] : p_t;
        float ce = sw[t] * (-__logf(p_t));
        float ptv = __expf(-ce);
        float om = 1.0f - ptv;
        accF += om * om * ce;

        unsigned rmv = rm[p];
#pragma unroll
        for (int c = 0; c < 7; c++) {
            float prc = pr[c];
            bool is = (c == t);
            sumP[c] += prc;
            if (is) { inter[c] += prc; cnt[c] += 1.0f; }
            float arg = is ? (prc + 1e-7f) : (1.0f - prc + 1e-7f);
            float bw = 1.0f + 4.0f * (float)((rmv >> c) & 1u);
            accB -= bw * __logf(arg);
        }

        // topo: dynamic-plane 3x3 gather
        if ((unsigned)(t - 2) < 5u) {
            int pl = t * 1164;
            float s = 0.f;
#pragma unroll
            for (int dy = -1; dy <= 1; dy++) {
#pragma unroll
                for (int dx = -1; dx <= 1; dx++) {
                    int np = hp + dy * 34 + dx;
                    float pn = __half2float(__ushort_as_half(sp[pl + np]));
                    int sn = st[(cy + 3 + dy) * 38 + (cx + 3 + dx)];
                    s += pn - ((sn == t) ? 1.0f : 0.0f);
                }
            }
            float val = fabsf(s) * (1.0f / 9.0f);
#pragma unroll
            for (int j = 0; j < 5; j++) num[j] += (t == j + 2) ? val : 0.f;
        }
    }

    // ---- phase C: reduce + plain double atomics ----
    float vals[28];
    vals[0] = accF; vals[1] = accB;
#pragma unroll
    for (int c = 0; c < 7; c++) { vals[2+c] = sumP[c]; vals[9+c] = inter[c]; vals[16+c] = cnt[c]; }
#pragma unroll
    for (int j = 0; j < 5; j++) vals[23+j] = num[j];

    int lane = tid & 63, wid = tid >> 6;
#pragma unroll
    for (int i = 0; i < 28; i++) {
        float v = vals[i];
#pragma unroll
        for (int o = 32; o > 0; o >>= 1) v += __shfl_down(v, o, 64);
        if (lane == 0) sred[wid * 28 + i] = v;
    }
    __syncthreads();
    if (tid < 28) {
        float s = sred[tid] + sred[28 + tid] + sred[56 + tid] + sred[84 + tid];
        atomicAdd(&acc[tid], (double)s);
    }
}

// ---------------------------------------------------------------------------
__global__ void finalize_kernel(const double* __restrict__ acc, float* __restrict__ out) {
    if (threadIdx.x == 0 && blockIdx.x == 0) {
        double focal = acc[0] / (double)((size_t)BB * HW);
        double bound = acc[1] / (double)((size_t)BB * CC * HW);
        double dice = 0.0;
#pragma unroll
        for (int c = 0; c < 7; c++) {
            double uni = acc[2 + c] + acc[16 + c];
            dice += 1.0 - (2.0 * acc[9 + c] + 1e-6) / (uni + 1e-6);
        }
        dice *= (1.0 / 7.0);
        double topo = 0.0;
#pragma unroll
        for (int j = 0; j < 5; j++) {
            double ms = acc[18 + j];
            double nm = acc[23 + j];
            topo += (ms >= 1.0) ? nm / fmax(ms, 1.0) : 0.0;
        }
        topo *= (1.0 / 5.0);
        out[0] = (float)(0.3 * focal + 0.3 * dice + 0.2 * bound + 0.2 * topo);
    }
}

extern "C" void kernel_launch(void* const* d_in, const int* in_sizes, int n_in,
                              void* d_out, int out_size, void* d_ws, size_t ws_size,
                              hipStream_t stream) {
    const float* logits = (const float*)d_in[0];
    const int* tgt = (const int*)d_in[1];
    const float* cw = (const float*)d_in[2];
    float* out = (float*)d_out;

    double* acc = (double*)d_ws;
    hipMemsetAsync(d_ws, 0, 256, stream);

    dim3 grid(WW / 32, HH / 32, BB);
    main_kernel<<<grid, 256, 0, stream>>>(logits, tgt, cw, acc);
    finalize_kernel<<<1, 64, 0, stream>>>(acc, out);
}

// Round 6
// 164.237 us; speedup vs baseline: 1.0165x; 1.0165x over previous
//
#include <hip/hip_runtime.h>
#include <hip/hip_fp16.h>

#define BB 8
#define CC 7
#define HH 512
#define WW 512
#define HW (HH*WW)

// Lessons encoded here:
//  - NO per-block __threadfence/ticket finalize (R2/R3: +100us from L2 drain).
//  - f16 in LDS only planar stride-2 (R2: 16B-stride pack = 8-way conflict).
//  - Occupancy is not the lever (R5: 33->48% occ, same 88us). The lever is
//    latency exposure: issue ALL global loads (float4/int4) up front, consume
//    once; keep interior probs in f32 registers; LDS only for topo neighbors.

__device__ __forceinline__ void softmax7x4(float4 a[7]) {
#pragma unroll
    for (int c = 0; c < 7; c++) {
        a[c].x = __expf(a[c].x); a[c].y = __expf(a[c].y);
        a[c].z = __expf(a[c].z); a[c].w = __expf(a[c].w);
    }
    float4 se = a[0];
#pragma unroll
    for (int c = 1; c < 7; c++) { se.x += a[c].x; se.y += a[c].y; se.z += a[c].z; se.w += a[c].w; }
    float ix = 1.f/se.x, iy = 1.f/se.y, iz = 1.f/se.z, iw = 1.f/se.w;
#pragma unroll
    for (int c = 0; c < 7; c++) { a[c].x *= ix; a[c].y *= iy; a[c].z *= iz; a[c].w *= iw; }
}

__device__ __forceinline__ void write_planes(unsigned short* sp, const float4 a[7], int r, int cI) {
#pragma unroll
    for (int c = 2; c < 7; c++) {
        unsigned lo = (unsigned)__half_as_ushort(__float2half_rn(a[c].x))
                    | ((unsigned)__half_as_ushort(__float2half_rn(a[c].y)) << 16);
        unsigned hi = (unsigned)__half_as_ushort(__float2half_rn(a[c].z))
                    | ((unsigned)__half_as_ushort(__float2half_rn(a[c].w)) << 16);
        uint2 w2 = make_uint2(lo, hi);
        *(uint2*)&sp[(c - 2) * 1360 + r * 40 + cI * 4] = w2;
    }
}

__device__ __forceinline__ void pixel_body(const float pr[7], int t, unsigned rmv,
                                           const unsigned short* sp, const unsigned char* st,
                                           const float* sw, int cy, int cx,
                                           float& accF, float& accB,
                                           float* sumP, float* inter, float* cnt, float* num) {
    // focal (register 7-way select)
    float p_t = pr[0];
#pragma unroll
    for (int c = 1; c < 7; c++) p_t = (t == c) ? pr[c] : p_t;
    float ce = sw[t] * (-__logf(p_t));
    float ptv = __expf(-ce);
    float om = 1.0f - ptv;
    accF += om * om * ce;

    // dice partials + bce via 2-log product trick
    float prodA = 1.0f, prodB = 1.0f;
#pragma unroll
    for (int c = 0; c < 7; c++) {
        float p = pr[c];
        bool is = (c == t);
        sumP[c] += p;
        if (is) { inter[c] += p; cnt[c] += 1.0f; }
        float arg = is ? (p + 1e-7f) : (1.0f - p + 1e-7f);
        prodA *= arg;
        prodB *= ((rmv >> c) & 1u) ? arg : 1.0f;
    }
    accB -= __logf(prodA) + 4.0f * __logf(prodB);

    // topo: 3x3 of (probs - onehot) on channel t, t in [2,7)
    if ((unsigned)(t - 2) < 5u) {
        const unsigned short* pl = sp + (t - 2) * 1360;
        int base = (cy + 1) * 40 + (cx + 4);
        int sb = (cy + 3) * 40 + (cx + 4);
        float s = 0.f;
#pragma unroll
        for (int dy = -1; dy <= 1; dy++) {
#pragma unroll
            for (int dx = -1; dx <= 1; dx++) {
                float pn = __half2float(__ushort_as_half(pl[base + dy * 40 + dx]));
                s += pn - ((st[sb + dy * 40 + dx] == t) ? 1.0f : 0.0f);
            }
        }
        float val = fabsf(s) * (1.0f / 9.0f);
#pragma unroll
        for (int q = 0; q < 5; q++) num[q] += (t == q + 2) ? val : 0.f;
    }
}

// One block = 32x32 interior pixels. Logits tile: 34 rows x 40 cols (x: +-4
// aligned, y: +-1), 4-pixel float4 groups; 256 interior groups (1:1 thread) +
// 84 halo groups (threads 0..83). Targets tile: 38 rows x 40 cols via int4.
__global__ __launch_bounds__(256) void main_kernel(const float* __restrict__ logits,
                                                   const int* __restrict__ tgt,
                                                   const float* __restrict__ cw,
                                                   double* __restrict__ acc) {
    __shared__ unsigned short sp[5 * 1360];   // f16 planes ch2..6, 34x40, 13.6KB
    __shared__ unsigned char st[40 * 38];     // targets (255 = OOB)
    __shared__ unsigned char bm[36 * 36];
    __shared__ unsigned char hm[36 * 32];
    __shared__ unsigned char rm[1024];
    __shared__ float sw[8];
    __shared__ float sred[112];

    const int tid = threadIdx.x;
    const int b = blockIdx.z;
    const int gx0 = blockIdx.x * 32, gy0 = blockIdx.y * 32;
    if (tid < 7) sw[tid] = cw[tid];

    const float* lg = logits + (size_t)b * CC * HW;
    const int* tg = tgt + (size_t)b * HW;

    // ---- issue ALL global loads up front ----
    int4 tv0, tv1; bool tvld0, tvld1;
    {
        int r = tid / 10, cI = tid - r * 10;
        int y = gy0 - 3 + r, xs = gx0 - 4 + cI * 4;
        tvld0 = ((unsigned)y < HH) && ((unsigned)xs < WW);
        size_t off = tvld0 ? ((size_t)y * WW + xs) : 0;
        tv0 = *(const int4*)(tg + off);
    }
    {
        int g = tid + 256; int gc = (g < 380) ? g : 0;
        int r = gc / 10, cI = gc - r * 10;
        int y = gy0 - 3 + r, xs = gx0 - 4 + cI * 4;
        tvld1 = (g < 380) && ((unsigned)y < HH) && ((unsigned)xs < WW);
        size_t off = tvld1 ? ((size_t)y * WW + xs) : 0;
        tv1 = *(const int4*)(tg + off);
    }
    const int rI = 1 + (tid >> 3), cII = 1 + (tid & 7);   // interior group
    float4 aI[7];
    {
        const float* p0 = lg + (size_t)(gy0 - 1 + rI) * WW + (gx0 - 4 + cII * 4);
#pragma unroll
        for (int c = 0; c < 7; c++) aI[c] = *(const float4*)(p0 + (size_t)c * HW);
    }
    float4 aH[7]; bool hvld = false; int hr = 0, hc = 0;
    if (tid < 84) {
        if (tid < 10)      { hr = 0;  hc = tid; }
        else if (tid < 20) { hr = 33; hc = tid - 10; }
        else { int e = tid - 20; hr = 1 + (e >> 1); hc = (e & 1) ? 9 : 0; }
        int y = gy0 - 1 + hr, xs = gx0 - 4 + hc * 4;
        hvld = ((unsigned)y < HH) && ((unsigned)xs < WW);
        size_t off = hvld ? ((size_t)y * WW + xs) : 0;
        const float* p0 = lg + off;
#pragma unroll
        for (int c = 0; c < 7; c++) aH[c] = *(const float4*)(p0 + (size_t)c * HW);
    }

    // ---- st writes (waits int4 loads only) ----
    {
        int r = tid / 10, cI = tid - r * 10;
        unsigned w = tvld0 ? ((unsigned)tv0.x | ((unsigned)tv0.y << 8) |
                              ((unsigned)tv0.z << 16) | ((unsigned)tv0.w << 24))
                           : 0xFFFFFFFFu;
        *(unsigned*)&st[r * 40 + cI * 4] = w;
    }
    if (tid + 256 < 380) {
        int g = tid + 256;
        int r = g / 10, cI = g - r * 10;
        unsigned w = tvld1 ? ((unsigned)tv1.x | ((unsigned)tv1.y << 8) |
                              ((unsigned)tv1.z << 16) | ((unsigned)tv1.w << 24))
                           : 0xFFFFFFFFu;
        *(unsigned*)&st[r * 40 + cI * 4] = w;
    }

    // ---- softmax from registers (single exposed latency window) ----
    softmax7x4(aI);
    write_planes(sp, aI, rI, cII);
    if (tid < 84) {
        if (hvld) {
            softmax7x4(aH);
        } else {
#pragma unroll
            for (int c = 0; c < 7; c++) aH[c] = make_float4(0.f, 0.f, 0.f, 0.f);
        }
        write_planes(sp, aH, hr, hc);
    }
    __syncthreads();

    // ---- boundary bits (+-2), zero-padded laplacian semantics ----
    for (int p = tid; p < 1296; p += 256) {
        int by = p / 36, bx = p - by * 36;
        int y = gy0 - 2 + by, x = gx0 - 2 + bx;
        unsigned bits = 0;
        if ((unsigned)y < HH && (unsigned)x < WW) {
            int si = (by + 1) * 40 + (bx + 2);
            int t = st[si];
            unsigned orm = 0; int nfirst = -1, same = 1, ninb = 0;
            int n;
            n = st[si - 40]; if (n != 255) { orm |= 1u << n; if (nfirst < 0) nfirst = n; else same &= (n == nfirst); ninb++; }
            n = st[si + 40]; if (n != 255) { orm |= 1u << n; if (nfirst < 0) nfirst = n; else same &= (n == nfirst); ninb++; }
            n = st[si - 1];  if (n != 255) { orm |= 1u << n; if (nfirst < 0) nfirst = n; else same &= (n == nfirst); ninb++; }
            n = st[si + 1];  if (n != 255) { orm |= 1u << n; if (nfirst < 0) nfirst = n; else same &= (n == nfirst); ninb++; }
            unsigned andm = (ninb == 4 && same) ? (1u << nfirst) : 0u;
            unsigned cbit = 1u << t;
            bits = (orm & ~cbit) | (cbit & ~andm);
        }
        bm[p] = (unsigned char)bits;
    }
    __syncthreads();
    // ---- horizontal 5-OR ----
    for (int p = tid; p < 1152; p += 256) {
        int hy = p >> 5, hx = p & 31;
        const unsigned char* r = &bm[hy * 36 + hx];
        hm[p] = (unsigned char)(r[0] | r[1] | r[2] | r[3] | r[4]);
    }
    __syncthreads();
    // ---- vertical 5-OR -> region byte ----
#pragma unroll
    for (int k = 0; k < 4; k++) {
        int p = tid + k * 256;
        const unsigned char* hc2 = &hm[(p >> 5) * 32 + (p & 31)];
        rm[p] = (unsigned char)(hc2[0] | hc2[32] | hc2[64] | hc2[96] | hc2[128]);
    }
    __syncthreads();

    // ---- phase B: 4 own pixels from f32 registers ----
    float accF = 0.f, accB = 0.f;
    float sumP[7] = {0,0,0,0,0,0,0};
    float inter[7] = {0,0,0,0,0,0,0};
    float cnt[7] = {0,0,0,0,0,0,0};
    float num[5] = {0,0,0,0,0};
    const int cy = tid >> 3, cxb = (tid & 7) * 4;
    unsigned rmv4 = *(unsigned*)&rm[cy * 32 + cxb];
    unsigned t4 = *(unsigned*)&st[(cy + 3) * 40 + cxb + 4];
    {
        float pr[7] = {aI[0].x, aI[1].x, aI[2].x, aI[3].x, aI[4].x, aI[5].x, aI[6].x};
        pixel_body(pr, (int)(t4 & 255u), rmv4 & 255u, sp, st, sw, cy, cxb + 0,
                   accF, accB, sumP, inter, cnt, num);
    }
    {
        float pr[7] = {aI[0].y, aI[1].y, aI[2].y, aI[3].y, aI[4].y, aI[5].y, aI[6].y};
        pixel_body(pr, (int)((t4 >> 8) & 255u), (rmv4 >> 8) & 255u, sp, st, sw, cy, cxb + 1,
                   accF, accB, sumP, inter, cnt, num);
    }
    {
        float pr[7] = {aI[0].z, aI[1].z, aI[2].z, aI[3].z, aI[4].z, aI[5].z, aI[6].z};
        pixel_body(pr, (int)((t4 >> 16) & 255u), (rmv4 >> 16) & 255u, sp, st, sw, cy, cxb + 2,
                   accF, accB, sumP, inter, cnt, num);
    }
    {
        float pr[7] = {aI[0].w, aI[1].w, aI[2].w, aI[3].w, aI[4].w, aI[5].w, aI[6].w};
        pixel_body(pr, (int)((t4 >> 24) & 255u), (rmv4 >> 24) & 255u, sp, st, sw, cy, cxb + 3,
                   accF, accB, sumP, inter, cnt, num);
    }

    // ---- phase C: reduce + plain double atomics ----
    float vals[28];
    vals[0] = accF; vals[1] = accB;
#pragma unroll
    for (int c = 0; c < 7; c++) { vals[2+c] = sumP[c]; vals[9+c] = inter[c]; vals[16+c] = cnt[c]; }
#pragma unroll
    for (int j = 0; j < 5; j++) vals[23+j] = num[j];

    int lane = tid & 63, wid = tid >> 6;
#pragma unroll
    for (int i = 0; i < 28; i++) {
        float v = vals[i];
#pragma unroll
        for (int o = 32; o > 0; o >>= 1) v += __shfl_down(v, o, 64);
        if (lane == 0) sred[wid * 28 + i] = v;
    }
    __syncthreads();
    if (tid < 28) {
        float s = sred[tid] + sred[28 + tid] + sred[56 + tid] + sred[84 + tid];
        atomicAdd(&acc[tid], (double)s);
    }
}

// ---------------------------------------------------------------------------
__global__ void finalize_kernel(const double* __restrict__ acc, float* __restrict__ out) {
    if (threadIdx.x == 0 && blockIdx.x == 0) {
        double focal = acc[0] / (double)((size_t)BB * HW);
        double bound = acc[1] / (double)((size_t)BB * CC * HW);
        double dice = 0.0;
#pragma unroll
        for (int c = 0; c < 7; c++) {
            double uni = acc[2 + c] + acc[16 + c];
            dice += 1.0 - (2.0 * acc[9 + c] + 1e-6) / (uni + 1e-6);
        }
        dice *= (1.0 / 7.0);
        double topo = 0.0;
#pragma unroll
        for (int j = 0; j < 5; j++) {
            double ms = acc[18 + j];
            double nm = acc[23 + j];
            topo += (ms >= 1.0) ? nm / fmax(ms, 1.0) : 0.0;
        }
        topo *= (1.0 / 5.0);
        out[0] = (float)(0.3 * focal + 0.3 * dice + 0.2 * bound + 0.2 * topo);
    }
}

extern "C" void kernel_launch(void* const* d_in, const int* in_sizes, int n_in,
                              void* d_out, int out_size, void* d_ws, size_t ws_size,
                              hipStream_t stream) {
    const float* logits = (const float*)d_in[0];
    const int* tgt = (const int*)d_in[1];
    const float* cw = (const float*)d_in[2];
    float* out = (float*)d_out;

    double* acc = (double*)d_ws;
    hipMemsetAsync(d_ws, 0, 256, stream);

    dim3 grid(WW / 32, HH / 32, BB);
    main_kernel<<<grid, 256, 0, stream>>>(logits, tgt, cw, acc);
    finalize_kernel<<<1, 64, 0, stream>>>(acc, out);
}

// Round 8
// 160.468 us; speedup vs baseline: 1.0404x; 1.0235x over previous
//
#include <hip/hip_runtime.h>
#include <hip/hip_fp16.h>

#define BB 8
#define CC 7
#define HH 512
#define WW 512
#define HW (HH*WW)
#define NBLK 2048   // (512/32)*(512/32)*8

// Lessons encoded:
//  - NO per-block __threadfence/ticket (R2/R3: +100us L2 drain).
//  - NO 28-way same-address double atomics from 2048 co-resident blocks
//    (R1-R6: invariant ~85us regardless of structure => L2 RMW serialization).
//    Each block stores 28 f32 partials to unique slots; reduce kernel sums.
//  - f16 LDS only planar stride-2 (R2: 16B-stride pack = 8-way conflict).
//  - All global loads issued up front as float4/int4; probs stay in registers.

__device__ __forceinline__ void softmax7x4(float4 a[7]) {
#pragma unroll
    for (int c = 0; c < 7; c++) {
        a[c].x = __expf(a[c].x); a[c].y = __expf(a[c].y);
        a[c].z = __expf(a[c].z); a[c].w = __expf(a[c].w);
    }
    float4 se = a[0];
#pragma unroll
    for (int c = 1; c < 7; c++) { se.x += a[c].x; se.y += a[c].y; se.z += a[c].z; se.w += a[c].w; }
    float ix = 1.f/se.x, iy = 1.f/se.y, iz = 1.f/se.z, iw = 1.f/se.w;
#pragma unroll
    for (int c = 0; c < 7; c++) { a[c].x *= ix; a[c].y *= iy; a[c].z *= iz; a[c].w *= iw; }
}

__device__ __forceinline__ void write_planes(unsigned short* sp, const float4 a[7], int r, int cI) {
#pragma unroll
    for (int c = 2; c < 7; c++) {
        unsigned lo = (unsigned)__half_as_ushort(__float2half_rn(a[c].x))
                    | ((unsigned)__half_as_ushort(__float2half_rn(a[c].y)) << 16);
        unsigned hi = (unsigned)__half_as_ushort(__float2half_rn(a[c].z))
                    | ((unsigned)__half_as_ushort(__float2half_rn(a[c].w)) << 16);
        uint2 w2 = make_uint2(lo, hi);
        *(uint2*)&sp[(c - 2) * 1360 + r * 40 + cI * 4] = w2;
    }
}

__device__ __forceinline__ void pixel_body(const float pr[7], int t, unsigned rmv,
                                           const unsigned short* sp, const unsigned char* st,
                                           const float* sw, int cy, int cx,
                                           float& accF, float& accB,
                                           float* sumP, float* inter, float* cnt, float* num) {
    float p_t = pr[0];
#pragma unroll
    for (int c = 1; c < 7; c++) p_t = (t == c) ? pr[c] : p_t;
    float ce = sw[t] * (-__logf(p_t));
    float ptv = __expf(-ce);
    float om = 1.0f - ptv;
    accF += om * om * ce;

    float prodA = 1.0f, prodB = 1.0f;
#pragma unroll
    for (int c = 0; c < 7; c++) {
        float p = pr[c];
        bool is = (c == t);
        sumP[c] += p;
        if (is) { inter[c] += p; cnt[c] += 1.0f; }
        float arg = is ? (p + 1e-7f) : (1.0f - p + 1e-7f);
        prodA *= arg;
        prodB *= ((rmv >> c) & 1u) ? arg : 1.0f;
    }
    accB -= __logf(prodA) + 4.0f * __logf(prodB);

    if ((unsigned)(t - 2) < 5u) {
        const unsigned short* pl = sp + (t - 2) * 1360;
        int base = (cy + 1) * 40 + (cx + 4);
        int sb = (cy + 3) * 40 + (cx + 4);
        float s = 0.f;
#pragma unroll
        for (int dy = -1; dy <= 1; dy++) {
#pragma unroll
            for (int dx = -1; dx <= 1; dx++) {
                float pn = __half2float(__ushort_as_half(pl[base + dy * 40 + dx]));
                s += pn - ((st[sb + dy * 40 + dx] == t) ? 1.0f : 0.0f);
            }
        }
        float val = fabsf(s) * (1.0f / 9.0f);
#pragma unroll
        for (int q = 0; q < 5; q++) num[q] += (t == q + 2) ? val : 0.f;
    }
}

__global__ __launch_bounds__(256) void main_kernel(const float* __restrict__ logits,
                                                   const int* __restrict__ tgt,
                                                   const float* __restrict__ cw,
                                                   float* __restrict__ part) {
    __shared__ unsigned short sp[5 * 1360];
    __shared__ unsigned char st[40 * 38];
    __shared__ unsigned char bm[36 * 36];
    __shared__ unsigned char hm[36 * 32];
    __shared__ unsigned char rm[1024];
    __shared__ float sw[8];
    __shared__ float sred[112];

    const int tid = threadIdx.x;
    const int b = blockIdx.z;
    const int gx0 = blockIdx.x * 32, gy0 = blockIdx.y * 32;
    if (tid < 7) sw[tid] = cw[tid];

    const float* lg = logits + (size_t)b * CC * HW;
    const int* tg = tgt + (size_t)b * HW;

    // ---- issue ALL global loads up front ----
    int4 tv0, tv1; bool tvld0, tvld1;
    {
        int r = tid / 10, cI = tid - r * 10;
        int y = gy0 - 3 + r, xs = gx0 - 4 + cI * 4;
        tvld0 = ((unsigned)y < HH) && ((unsigned)xs < WW);
        size_t off = tvld0 ? ((size_t)y * WW + xs) : 0;
        tv0 = *(const int4*)(tg + off);
    }
    {
        int g = tid + 256; int gc = (g < 380) ? g : 0;
        int r = gc / 10, cI = gc - r * 10;
        int y = gy0 - 3 + r, xs = gx0 - 4 + cI * 4;
        tvld1 = (g < 380) && ((unsigned)y < HH) && ((unsigned)xs < WW);
        size_t off = tvld1 ? ((size_t)y * WW + xs) : 0;
        tv1 = *(const int4*)(tg + off);
    }
    const int rI = 1 + (tid >> 3), cII = 1 + (tid & 7);
    float4 aI[7];
    {
        const float* p0 = lg + (size_t)(gy0 - 1 + rI) * WW + (gx0 - 4 + cII * 4);
#pragma unroll
        for (int c = 0; c < 7; c++) aI[c] = *(const float4*)(p0 + (size_t)c * HW);
    }
    float4 aH[7]; bool hvld = false; int hr = 0, hc = 0;
    if (tid < 84) {
        if (tid < 10)      { hr = 0;  hc = tid; }
        else if (tid < 20) { hr = 33; hc = tid - 10; }
        else { int e = tid - 20; hr = 1 + (e >> 1); hc = (e & 1) ? 9 : 0; }
        int y = gy0 - 1 + hr, xs = gx0 - 4 + hc * 4;
        hvld = ((unsigned)y < HH) && ((unsigned)xs < WW);
        size_t off = hvld ? ((size_t)y * WW + xs) : 0;
        const float* p0 = lg + off;
#pragma unroll
        for (int c = 0; c < 7; c++) aH[c] = *(const float4*)(p0 + (size_t)c * HW);
    }

    // ---- st writes ----
    {
        int r = tid / 10, cI = tid - r * 10;
        unsigned w = tvld0 ? ((unsigned)tv0.x | ((unsigned)tv0.y << 8) |
                              ((unsigned)tv0.z << 16) | ((unsigned)tv0.w << 24))
                           : 0xFFFFFFFFu;
        *(unsigned*)&st[r * 40 + cI * 4] = w;
    }
    if (tid + 256 < 380) {
        int g = tid + 256;
        int r = g / 10, cI = g - r * 10;
        unsigned w = tvld1 ? ((unsigned)tv1.x | ((unsigned)tv1.y << 8) |
                              ((unsigned)tv1.z << 16) | ((unsigned)tv1.w << 24))
                           : 0xFFFFFFFFu;
        *(unsigned*)&st[r * 40 + cI * 4] = w;
    }

    // ---- softmax from registers ----
    softmax7x4(aI);
    write_planes(sp, aI, rI, cII);
    if (tid < 84) {
        if (hvld) {
            softmax7x4(aH);
        } else {
#pragma unroll
            for (int c = 0; c < 7; c++) aH[c] = make_float4(0.f, 0.f, 0.f, 0.f);
        }
        write_planes(sp, aH, hr, hc);
    }
    __syncthreads();

    // ---- boundary bits (+-2) ----
    for (int p = tid; p < 1296; p += 256) {
        int by = p / 36, bx = p - by * 36;
        int y = gy0 - 2 + by, x = gx0 - 2 + bx;
        unsigned bits = 0;
        if ((unsigned)y < HH && (unsigned)x < WW) {
            int si = (by + 1) * 40 + (bx + 2);
            int t = st[si];
            unsigned orm = 0; int nfirst = -1, same = 1, ninb = 0;
            int n;
            n = st[si - 40]; if (n != 255) { orm |= 1u << n; if (nfirst < 0) nfirst = n; else same &= (n == nfirst); ninb++; }
            n = st[si + 40]; if (n != 255) { orm |= 1u << n; if (nfirst < 0) nfirst = n; else same &= (n == nfirst); ninb++; }
            n = st[si - 1];  if (n != 255) { orm |= 1u << n; if (nfirst < 0) nfirst = n; else same &= (n == nfirst); ninb++; }
            n = st[si + 1];  if (n != 255) { orm |= 1u << n; if (nfirst < 0) nfirst = n; else same &= (n == nfirst); ninb++; }
            unsigned andm = (ninb == 4 && same) ? (1u << nfirst) : 0u;
            unsigned cbit = 1u << t;
            bits = (orm & ~cbit) | (cbit & ~andm);
        }
        bm[p] = (unsigned char)bits;
    }
    __syncthreads();
    for (int p = tid; p < 1152; p += 256) {
        int hy = p >> 5, hx = p & 31;
        const unsigned char* r = &bm[hy * 36 + hx];
        hm[p] = (unsigned char)(r[0] | r[1] | r[2] | r[3] | r[4]);
    }
    __syncthreads();
#pragma unroll
    for (int k = 0; k < 4; k++) {
        int p = tid + k * 256;
        const unsigned char* hc2 = &hm[(p >> 5) * 32 + (p & 31)];
        rm[p] = (unsigned char)(hc2[0] | hc2[32] | hc2[64] | hc2[96] | hc2[128]);
    }
    __syncthreads();

    // ---- phase B ----
    float accF = 0.f, accB = 0.f;
    float sumP[7] = {0,0,0,0,0,0,0};
    float inter[7] = {0,0,0,0,0,0,0};
    float cnt[7] = {0,0,0,0,0,0,0};
    float num[5] = {0,0,0,0,0};
    const int cy = tid >> 3, cxb = (tid & 7) * 4;
    unsigned rmv4 = *(unsigned*)&rm[cy * 32 + cxb];
    unsigned t4 = *(unsigned*)&st[(cy + 3) * 40 + cxb + 4];
    {
        float pr[7] = {aI[0].x, aI[1].x, aI[2].x, aI[3].x, aI[4].x, aI[5].x, aI[6].x};
        pixel_body(pr, (int)(t4 & 255u), rmv4 & 255u, sp, st, sw, cy, cxb + 0,
                   accF, accB, sumP, inter, cnt, num);
    }
    {
        float pr[7] = {aI[0].y, aI[1].y, aI[2].y, aI[3].y, aI[4].y, aI[5].y, aI[6].y};
        pixel_body(pr, (int)((t4 >> 8) & 255u), (rmv4 >> 8) & 255u, sp, st, sw, cy, cxb + 1,
                   accF, accB, sumP, inter, cnt, num);
    }
    {
        float pr[7] = {aI[0].z, aI[1].z, aI[2].z, aI[3].z, aI[4].z, aI[5].z, aI[6].z};
        pixel_body(pr, (int)((t4 >> 16) & 255u), (rmv4 >> 16) & 255u, sp, st, sw, cy, cxb + 2,
                   accF, accB, sumP, inter, cnt, num);
    }
    {
        float pr[7] = {aI[0].w, aI[1].w, aI[2].w, aI[3].w, aI[4].w, aI[5].w, aI[6].w};
        pixel_body(pr, (int)((t4 >> 24) & 255u), (rmv4 >> 24) & 255u, sp, st, sw, cy, cxb + 3,
                   accF, accB, sumP, inter, cnt, num);
    }

    // ---- phase C: reduce + contention-free per-block partial store ----
    float vals[28];
    vals[0] = accF; vals[1] = accB;
#pragma unroll
    for (int c = 0; c < 7; c++) { vals[2+c] = sumP[c]; vals[9+c] = inter[c]; vals[16+c] = cnt[c]; }
#pragma unroll
    for (int j = 0; j < 5; j++) vals[23+j] = num[j];

    int lane = tid & 63, wid = tid >> 6;
#pragma unroll
    for (int i = 0; i < 28; i++) {
        float v = vals[i];
#pragma unroll
        for (int o = 32; o > 0; o >>= 1) v += __shfl_down(v, o, 64);
        if (lane == 0) sred[wid * 28 + i] = v;
    }
    __syncthreads();
    if (tid < 28) {
        float s = sred[tid] + sred[28 + tid] + sred[56 + tid] + sred[84 + tid];
        int bid = (blockIdx.z * gridDim.y + blockIdx.y) * gridDim.x + blockIdx.x;
        part[tid * NBLK + bid] = s;   // plain store, no contention
    }
}

// ---------------------------------------------------------------------------
// Reduce 28 x 2048 partials (coalesced, f64 accum) + final loss formula.
__global__ __launch_bounds__(256) void reduce_kernel(const float* __restrict__ part,
                                                     float* __restrict__ out) {
    __shared__ double swred[4];
    __shared__ double fin[28];
    const int tid = threadIdx.x;
    for (int j = 0; j < 28; j++) {
        double s = 0.0;
#pragma unroll
        for (int k = 0; k < NBLK / 256; k++) s += (double)part[j * NBLK + tid + k * 256];
#pragma unroll
        for (int o = 32; o > 0; o >>= 1) s += __shfl_down(s, o, 64);
        if ((tid & 63) == 0) swred[tid >> 6] = s;
        __syncthreads();
        if (tid == 0) fin[j] = swred[0] + swred[1] + swred[2] + swred[3];
        __syncthreads();
    }
    if (tid == 0) {
        double focal = fin[0] / (double)((size_t)BB * HW);
        double bound = fin[1] / (double)((size_t)BB * CC * HW);
        double dice = 0.0;
#pragma unroll
        for (int c = 0; c < 7; c++) {
            double uni = fin[2 + c] + fin[16 + c];
            dice += 1.0 - (2.0 * fin[9 + c] + 1e-6) / (uni + 1e-6);
        }
        dice *= (1.0 / 7.0);
        double topo = 0.0;
#pragma unroll
        for (int j = 0; j < 5; j++) {
            double ms = fin[18 + j];
            double nm = fin[23 + j];
            topo += (ms >= 1.0) ? nm / fmax(ms, 1.0) : 0.0;
        }
        topo *= (1.0 / 5.0);
        out[0] = (float)(0.3 * focal + 0.3 * dice + 0.2 * bound + 0.2 * topo);
    }
}

extern "C" void kernel_launch(void* const* d_in, const int* in_sizes, int n_in,
                              void* d_out, int out_size, void* d_ws, size_t ws_size,
                              hipStream_t stream) {
    const float* logits = (const float*)d_in[0];
    const int* tgt = (const int*)d_in[1];
    const float* cw = (const float*)d_in[2];
    float* out = (float*)d_out;
    float* part = (float*)d_ws;   // 28 * 2048 floats = 229 KB; fully overwritten

    dim3 grid(WW / 32, HH / 32, BB);
    main_kernel<<<grid, 256, 0, stream>>>(logits, tgt, cw, part);
    reduce_kernel<<<1, 256, 0, stream>>>(part, out);
}

// Round 9
// 135.776 us; speedup vs baseline: 1.2296x; 1.1819x over previous
//
#include <hip/hip_runtime.h>
#include <hip/hip_fp16.h>

#define BB 8
#define CC 7
#define HH 512
#define WW 512
#define HW (HH*WW)
#define NBLK 1024   // grid 16 x 8 x 8, each block does TWO vertical 32x32 tiles

// Lessons encoded:
//  - NO per-block __threadfence/ticket (R2/R3: +100us L2 drain).
//  - NO same-address double atomics from all blocks (R8: removing = -24us).
//  - NO __shfl_down reduction trees (ds_bpermute = LDS pipe, ~670 insts/blk):
//    DPP v_add (row_shr/row_bcast) on VALU pipe instead.
//  - Serial 28-iter reduce kernel was ~22us: parallel wave-per-counter now.
//  - f16 LDS only planar stride-2 (R2: 16B-stride pack = 8-way conflict).
//  - All loads float4/int4, issued early; tile2 loads prefetched before
//    tile1 compute (load/compute overlap across the tile pair).

__device__ __forceinline__ float dpp_red(float v) {
    // wave64 sum via DPP; result lands in lane 63.
#define STEP(ctrl) v += __int_as_float(__builtin_amdgcn_update_dpp(0, __float_as_int(v), ctrl, 0xF, 0xF, true))
    STEP(0x111); STEP(0x112); STEP(0x114); STEP(0x118);  // row_shr 1,2,4,8
    STEP(0x142); STEP(0x143);                            // row_bcast 15,31
#undef STEP
    return v;
}

__device__ __forceinline__ void softmax7x4(float4 a[7]) {
#pragma unroll
    for (int c = 0; c < 7; c++) {
        a[c].x = __expf(a[c].x); a[c].y = __expf(a[c].y);
        a[c].z = __expf(a[c].z); a[c].w = __expf(a[c].w);
    }
    float4 se = a[0];
#pragma unroll
    for (int c = 1; c < 7; c++) { se.x += a[c].x; se.y += a[c].y; se.z += a[c].z; se.w += a[c].w; }
    float ix = 1.f/se.x, iy = 1.f/se.y, iz = 1.f/se.z, iw = 1.f/se.w;
#pragma unroll
    for (int c = 0; c < 7; c++) { a[c].x *= ix; a[c].y *= iy; a[c].z *= iz; a[c].w *= iw; }
}

__device__ __forceinline__ void write_planes(unsigned short* sp, const float4 a[7], int r, int cI) {
#pragma unroll
    for (int c = 2; c < 7; c++) {
        unsigned lo = (unsigned)__half_as_ushort(__float2half_rn(a[c].x))
                    | ((unsigned)__half_as_ushort(__float2half_rn(a[c].y)) << 16);
        unsigned hi = (unsigned)__half_as_ushort(__float2half_rn(a[c].z))
                    | ((unsigned)__half_as_ushort(__float2half_rn(a[c].w)) << 16);
        *(uint2*)&sp[(c - 2) * 1360 + r * 40 + cI * 4] = make_uint2(lo, hi);
    }
}

__device__ __forceinline__ void pixel_body(const float pr[7], int t, unsigned rmv,
                                           const unsigned short* sp, const unsigned char* st,
                                           const float* sw, int cy, int cx,
                                           float& accF, float& accB,
                                           float* sumP, float* inter, float* cnt, float* num) {
    float p_t = pr[0];
#pragma unroll
    for (int c = 1; c < 7; c++) p_t = (t == c) ? pr[c] : p_t;
    float ce = sw[t] * (-__logf(p_t));
    float ptv = __expf(-ce);
    float om = 1.0f - ptv;
    accF += om * om * ce;

    float prodA = 1.0f, prodB = 1.0f;
#pragma unroll
    for (int c = 0; c < 7; c++) {
        float p = pr[c];
        bool is = (c == t);
        sumP[c] += p;
        if (is) { inter[c] += p; cnt[c] += 1.0f; }
        float arg = is ? (p + 1e-7f) : (1.0f - p + 1e-7f);
        prodA *= arg;
        prodB *= ((rmv >> c) & 1u) ? arg : 1.0f;
    }
    accB -= __logf(prodA) + 4.0f * __logf(prodB);

    if ((unsigned)(t - 2) < 5u) {
        const unsigned short* pl = sp + (t - 2) * 1360;
        int base = (cy + 1) * 40 + (cx + 4);
        int sb = (cy + 3) * 40 + (cx + 4);
        float s = 0.f;
#pragma unroll
        for (int dy = -1; dy <= 1; dy++) {
#pragma unroll
            for (int dx = -1; dx <= 1; dx++) {
                float pn = __half2float(__ushort_as_half(pl[base + dy * 40 + dx]));
                s += pn - ((st[sb + dy * 40 + dx] == t) ? 1.0f : 0.0f);
            }
        }
        float val = fabsf(s) * (1.0f / 9.0f);
#pragma unroll
        for (int q = 0; q < 5; q++) num[q] += (t == q + 2) ? val : 0.f;
    }
}

__device__ __forceinline__ void load_tgt(int tid, int gy0, int gx0, const int* tg,
                                         int4& tv0, bool& v0, int4& tv1, bool& v1) {
    {
        int r = tid / 10, cI = tid - r * 10;
        int y = gy0 - 3 + r, xs = gx0 - 4 + cI * 4;
        v0 = ((unsigned)y < HH) && ((unsigned)xs < WW);
        size_t off = v0 ? ((size_t)y * WW + xs) : 0;
        tv0 = *(const int4*)(tg + off);
    }
    {
        int g = tid + 256; int gc = (g < 380) ? g : 0;
        int r = gc / 10, cI = gc - r * 10;
        int y = gy0 - 3 + r, xs = gx0 - 4 + cI * 4;
        v1 = (g < 380) && ((unsigned)y < HH) && ((unsigned)xs < WW);
        size_t off = v1 ? ((size_t)y * WW + xs) : 0;
        tv1 = *(const int4*)(tg + off);
    }
}

__device__ __forceinline__ void store_st(int tid, int4 tv0, bool v0, int4 tv1, bool v1,
                                         unsigned char* st) {
    {
        int r = tid / 10, cI = tid - r * 10;
        unsigned w = v0 ? ((unsigned)tv0.x | ((unsigned)tv0.y << 8) |
                           ((unsigned)tv0.z << 16) | ((unsigned)tv0.w << 24))
                        : 0xFFFFFFFFu;
        *(unsigned*)&st[r * 40 + cI * 4] = w;
    }
    if (tid + 256 < 380) {
        int g = tid + 256;
        int r = g / 10, cI = g - r * 10;
        unsigned w = v1 ? ((unsigned)tv1.x | ((unsigned)tv1.y << 8) |
                           ((unsigned)tv1.z << 16) | ((unsigned)tv1.w << 24))
                        : 0xFFFFFFFFu;
        *(unsigned*)&st[r * 40 + cI * 4] = w;
    }
}

__device__ __forceinline__ void load_int(int tid, int gy0, int gx0, const float* lg, float4 aI[7]) {
    const int rI = 1 + (tid >> 3), cII = 1 + (tid & 7);
    const float* p0 = lg + (size_t)(gy0 - 1 + rI) * WW + (gx0 - 4 + cII * 4);
#pragma unroll
    for (int c = 0; c < 7; c++) aI[c] = *(const float4*)(p0 + (size_t)c * HW);
}

__device__ __forceinline__ void load_halo(int tid, int gy0, int gx0, const float* lg,
                                          float4 aH[7], bool& hvld, int& hr, int& hc) {
    hvld = false; hr = 0; hc = 0;
    if (tid < 84) {
        if (tid < 10)      { hr = 0;  hc = tid; }
        else if (tid < 20) { hr = 33; hc = tid - 10; }
        else { int e = tid - 20; hr = 1 + (e >> 1); hc = (e & 1) ? 9 : 0; }
        int y = gy0 - 1 + hr, xs = gx0 - 4 + hc * 4;
        hvld = ((unsigned)y < HH) && ((unsigned)xs < WW);
        size_t off = hvld ? ((size_t)y * WW + xs) : 0;
        const float* p0 = lg + off;
#pragma unroll
        for (int c = 0; c < 7; c++) aH[c] = *(const float4*)(p0 + (size_t)c * HW);
    }
}

__device__ __forceinline__ void halo_softmax_store(int tid, float4 aH[7], bool hvld,
                                                   int hr, int hc, unsigned short* sp) {
    if (tid < 84) {
        if (hvld) {
            softmax7x4(aH);
        } else {
#pragma unroll
            for (int c = 0; c < 7; c++) aH[c] = make_float4(0.f, 0.f, 0.f, 0.f);
        }
        write_planes(sp, aH, hr, hc);
    }
}

// boundary bits -> horizontal 5-OR -> vertical 5-OR. Contains 3 barriers.
__device__ __forceinline__ void build_masks(int tid, int gy0, int gx0,
                                            const unsigned char* st, unsigned char* bm,
                                            unsigned char* hm, unsigned char* rm) {
    for (int p = tid; p < 1296; p += 256) {
        int by = p / 36, bx = p - by * 36;
        int y = gy0 - 2 + by, x = gx0 - 2 + bx;
        unsigned bits = 0;
        if ((unsigned)y < HH && (unsigned)x < WW) {
            int si = (by + 1) * 40 + (bx + 2);
            int t = st[si];
            unsigned orm = 0; int nfirst = -1, same = 1, ninb = 0;
            int n;
            n = st[si - 40]; if (n != 255) { orm |= 1u << n; if (nfirst < 0) nfirst = n; else same &= (n == nfirst); ninb++; }
            n = st[si + 40]; if (n != 255) { orm |= 1u << n; if (nfirst < 0) nfirst = n; else same &= (n == nfirst); ninb++; }
            n = st[si - 1];  if (n != 255) { orm |= 1u << n; if (nfirst < 0) nfirst = n; else same &= (n == nfirst); ninb++; }
            n = st[si + 1];  if (n != 255) { orm |= 1u << n; if (nfirst < 0) nfirst = n; else same &= (n == nfirst); ninb++; }
            unsigned andm = (ninb == 4 && same) ? (1u << nfirst) : 0u;
            unsigned cbit = 1u << t;
            bits = (orm & ~cbit) | (cbit & ~andm);
        }
        bm[p] = (unsigned char)bits;
    }
    __syncthreads();
    for (int p = tid; p < 1152; p += 256) {
        int hy = p >> 5, hx = p & 31;
        const unsigned char* r = &bm[hy * 36 + hx];
        hm[p] = (unsigned char)(r[0] | r[1] | r[2] | r[3] | r[4]);
    }
    __syncthreads();
#pragma unroll
    for (int k = 0; k < 4; k++) {
        int p = tid + k * 256;
        const unsigned char* hc2 = &hm[(p >> 5) * 32 + (p & 31)];
        rm[p] = (unsigned char)(hc2[0] | hc2[32] | hc2[64] | hc2[96] | hc2[128]);
    }
    __syncthreads();
}

__device__ __forceinline__ void phase_b(int tid, const float4 aI[7],
                                        const unsigned short* sp, const unsigned char* st,
                                        const unsigned char* rm, const float* sw,
                                        float& accF, float& accB,
                                        float* sumP, float* inter, float* cnt, float* num) {
    const int cy = tid >> 3, cxb = (tid & 7) * 4;
    unsigned rmv4 = *(const unsigned*)&rm[cy * 32 + cxb];
    unsigned t4 = *(const unsigned*)&st[(cy + 3) * 40 + cxb + 4];
    {
        float pr[7] = {aI[0].x, aI[1].x, aI[2].x, aI[3].x, aI[4].x, aI[5].x, aI[6].x};
        pixel_body(pr, (int)(t4 & 255u), rmv4 & 255u, sp, st, sw, cy, cxb + 0,
                   accF, accB, sumP, inter, cnt, num);
    }
    {
        float pr[7] = {aI[0].y, aI[1].y, aI[2].y, aI[3].y, aI[4].y, aI[5].y, aI[6].y};
        pixel_body(pr, (int)((t4 >> 8) & 255u), (rmv4 >> 8) & 255u, sp, st, sw, cy, cxb + 1,
                   accF, accB, sumP, inter, cnt, num);
    }
    {
        float pr[7] = {aI[0].z, aI[1].z, aI[2].z, aI[3].z, aI[4].z, aI[5].z, aI[6].z};
        pixel_body(pr, (int)((t4 >> 16) & 255u), (rmv4 >> 16) & 255u, sp, st, sw, cy, cxb + 2,
                   accF, accB, sumP, inter, cnt, num);
    }
    {
        float pr[7] = {aI[0].w, aI[1].w, aI[2].w, aI[3].w, aI[4].w, aI[5].w, aI[6].w};
        pixel_body(pr, (int)((t4 >> 24) & 255u), (rmv4 >> 24) & 255u, sp, st, sw, cy, cxb + 3,
                   accF, accB, sumP, inter, cnt, num);
    }
}

__global__ __launch_bounds__(256) void main_kernel(const float* __restrict__ logits,
                                                   const int* __restrict__ tgt,
                                                   const float* __restrict__ cw,
                                                   float* __restrict__ part) {
    __shared__ unsigned short sp[5 * 1360];
    __shared__ unsigned char st[40 * 38];
    __shared__ unsigned char bm[36 * 36];
    __shared__ unsigned char hm[36 * 32];
    __shared__ unsigned char rm[1024];
    __shared__ float sw[8];
    __shared__ float sred[112];

    const int tid = threadIdx.x;
    const int b = blockIdx.z;
    const int gx0 = blockIdx.x * 32;
    const int gy0a = blockIdx.y * 64;        // tile 0
    const int gy0b = blockIdx.y * 64 + 32;   // tile 1
    if (tid < 7) sw[tid] = cw[tid];

    const float* lg = logits + (size_t)b * CC * HW;
    const int* tg = tgt + (size_t)b * HW;

    float accF = 0.f, accB = 0.f;
    float sumP[7] = {0,0,0,0,0,0,0};
    float inter[7] = {0,0,0,0,0,0,0};
    float cnt[7] = {0,0,0,0,0,0,0};
    float num[5] = {0,0,0,0,0};

    // ================= tile 0 =================
    int4 tv0, tv1; bool v0, v1;
    load_tgt(tid, gy0a, gx0, tg, tv0, v0, tv1, v1);
    float4 aI[7];
    load_int(tid, gy0a, gx0, lg, aI);
    float4 aH[7]; bool hvld; int hr, hc;
    load_halo(tid, gy0a, gx0, lg, aH, hvld, hr, hc);

    store_st(tid, tv0, v0, tv1, v1, st);
    {
        const int rI = 1 + (tid >> 3), cII = 1 + (tid & 7);
        softmax7x4(aI);
        write_planes(sp, aI, rI, cII);
    }
    halo_softmax_store(tid, aH, hvld, hr, hc, sp);

    // ---- prefetch tile 1 (interior + targets) before tile-0 compute ----
    int4 u0, u1; bool w0, w1;
    load_tgt(tid, gy0b, gx0, tg, u0, w0, u1, w1);
    float4 aJ[7];
    load_int(tid, gy0b, gx0, lg, aJ);

    __syncthreads();
    build_masks(tid, gy0a, gx0, st, bm, hm, rm);
    phase_b(tid, aI, sp, st, rm, sw, accF, accB, sumP, inter, cnt, num);
    __syncthreads();   // tile-0 LDS readers done; safe to overwrite

    // ================= tile 1 =================
    store_st(tid, u0, w0, u1, w1, st);
    {
        const int rI = 1 + (tid >> 3), cII = 1 + (tid & 7);
        softmax7x4(aJ);
        write_planes(sp, aJ, rI, cII);
    }
    load_halo(tid, gy0b, gx0, lg, aH, hvld, hr, hc);
    halo_softmax_store(tid, aH, hvld, hr, hc, sp);

    __syncthreads();
    build_masks(tid, gy0b, gx0, st, bm, hm, rm);
    phase_b(tid, aJ, sp, st, rm, sw, accF, accB, sumP, inter, cnt, num);

    // ================= phase C: DPP reduce + partial store =================
    float vals[28];
    vals[0] = accF; vals[1] = accB;
#pragma unroll
    for (int c = 0; c < 7; c++) { vals[2+c] = sumP[c]; vals[9+c] = inter[c]; vals[16+c] = cnt[c]; }
#pragma unroll
    for (int j = 0; j < 5; j++) vals[23+j] = num[j];

    const int lane = tid & 63, wid = tid >> 6;
#pragma unroll
    for (int i = 0; i < 28; i++) {
        float v = dpp_red(vals[i]);           // VALU pipe only
        if (lane == 63) sred[wid * 28 + i] = v;
    }
    __syncthreads();
    if (tid < 28) {
        float s = sred[tid] + sred[28 + tid] + sred[56 + tid] + sred[84 + tid];
        int bid = (blockIdx.z * gridDim.y + blockIdx.y) * gridDim.x + blockIdx.x;
        part[tid * NBLK + bid] = s;
    }
}

// ---------------------------------------------------------------------------
// Parallel reduce: 16 waves, wave w sums counters w and w+16 (f64, coalesced).
__global__ __launch_bounds__(1024) void reduce_kernel(const float* __restrict__ part,
                                                      float* __restrict__ out) {
    __shared__ double fin[28];
    const int tid = threadIdx.x;
    const int w = tid >> 6, lane = tid & 63;
    for (int j = w; j < 28; j += 16) {
        double s = 0.0;
#pragma unroll
        for (int k = 0; k < NBLK / 64; k++) s += (double)part[j * NBLK + lane + k * 64];
#pragma unroll
        for (int o = 32; o > 0; o >>= 1) s += __shfl_down(s, o, 64);
        if (lane == 0) fin[j] = s;
    }
    __syncthreads();
    if (tid == 0) {
        double focal = fin[0] / (double)((size_t)BB * HW);
        double bound = fin[1] / (double)((size_t)BB * CC * HW);
        double dice = 0.0;
#pragma unroll
        for (int c = 0; c < 7; c++) {
            double uni = fin[2 + c] + fin[16 + c];
            dice += 1.0 - (2.0 * fin[9 + c] + 1e-6) / (uni + 1e-6);
        }
        dice *= (1.0 / 7.0);
        double topo = 0.0;
#pragma unroll
        for (int j = 0; j < 5; j++) {
            double ms = fin[18 + j];
            double nm = fin[23 + j];
            topo += (ms >= 1.0) ? nm / fmax(ms, 1.0) : 0.0;
        }
        topo *= (1.0 / 5.0);
        out[0] = (float)(0.3 * focal + 0.3 * dice + 0.2 * bound + 0.2 * topo);
    }
}

extern "C" void kernel_launch(void* const* d_in, const int* in_sizes, int n_in,
                              void* d_out, int out_size, void* d_ws, size_t ws_size,
                              hipStream_t stream) {
    const float* logits = (const float*)d_in[0];
    const int* tgt = (const int*)d_in[1];
    const float* cw = (const float*)d_in[2];
    float* out = (float*)d_out;
    float* part = (float*)d_ws;   // 28 * 1024 floats = 114.7 KB; fully overwritten

    dim3 grid(WW / 32, HH / 64, BB);   // 16 x 8 x 8 = 1024 blocks, 2 tiles each
    main_kernel<<<grid, 256, 0, stream>>>(logits, tgt, cw, part);
    reduce_kernel<<<1, 1024, 0, stream>>>(part, out);
}